// Round 7
// baseline (117.232 us; speedup 1.0000x reference)
//
#include <hip/hip_runtime.h>
#include <math.h>

#define BB 8
#define CC 64
#define NN 4096
#define CI 8
#define GAMMA 0.1f
// exp(s/sqrt(8)) = exp2(s * log2(e)/sqrt(8)); folded into k in qkv.
#define SCALE (1.44269504088896f * 0.35355339059327f)
#define NSPLIT 8

typedef float v4f  __attribute__((ext_vector_type(4)));
typedef float v16f __attribute__((ext_vector_type(16)));
typedef __bf16 bf16x8 __attribute__((ext_vector_type(8)));
typedef unsigned int u32x2 __attribute__((ext_vector_type(2)));

__device__ __forceinline__ float fast_exp2(float x) {
    return __builtin_amdgcn_exp2f(x);
}

// Pack two f32 into one u32 of 2 bf16 (T12 recipe; no builtin on gfx950).
__device__ __forceinline__ unsigned int cvt_pk_bf16(float lo, float hi) {
    unsigned int r;
    asm("v_cvt_pk_bf16_f32 %0, %1, %2" : "=v"(r) : "v"(lo), "v"(hi));
    return r;
}

// qkv v3 = round-6 LDS-staged x, MINUS the attab zeroing pass (no longer
// needed: att now writes private per-split slices with plain stores, and
// red_kernel fully overwrites attab2 -> nothing requires zero-init).
// Grid (NN/32, BB); block 256 = 8 i-groups x 32 n.
// qbh[b][n][8], kbh[b][m][8] (k*SCALE), vbh[b][i][N] bf16.
__global__ __launch_bounds__(256) void qkv_kernel(
        const float* __restrict__ x,
        const float* __restrict__ Wq, const float* __restrict__ Wk,
        const float* __restrict__ Wv,
        __bf16* __restrict__ qbh, __bf16* __restrict__ kbh,
        __bf16* __restrict__ vbh) {
    __shared__ float sw[3 * CI * CC];     // 6 KB: Wq | Wk*SCALE | Wv
    __shared__ float xt[CC * 36];         // 9216 B: x tile [c][n_local], pitch 36
    __shared__ unsigned short sq[32 * 8]; // bf16 tile [n_local][i]
    __shared__ unsigned short sk[32 * 8];
    const int t = threadIdx.x;
    const int b  = blockIdx.y;
    const int n0 = blockIdx.x * 32;

    for (int idx = t; idx < CI * CC; idx += 256) {
        sw[idx]                = Wq[idx];
        sw[CI * CC + idx]      = Wk[idx] * SCALE;
        sw[2 * CI * CC + idx]  = Wv[idx];
    }
    // Stage x tile: 64 c x 32 n = 512 float4; 2 per thread.
    {
        const float* xb = x + ((size_t)b * CC) * NN + n0;
#pragma unroll
        for (int j = 0; j < 2; ++j) {
            int u = t + j * 256;
            int c = u >> 3, n4 = u & 7;
            v4f xv = *(const v4f*)(xb + (size_t)c * NN + n4 * 4);
            *(v4f*)(xt + c * 36 + n4 * 4) = xv;
        }
    }
    __syncthreads();

    const int i  = t >> 5;
    const int nl = t & 31;
    const int n = n0 + nl;
    const v4f* wq4 = (const v4f*)(sw + i * CC);
    const v4f* wk4 = (const v4f*)(sw + CI * CC + i * CC);
    const v4f* wv4 = (const v4f*)(sw + 2 * CI * CC + i * CC);
    float qa = 0.f, ka = 0.f, va = 0.f;
#pragma unroll 4
    for (int c4 = 0; c4 < CC / 4; ++c4) {
        v4f wq = wq4[c4], wk = wk4[c4], wv = wv4[c4];   // LDS broadcast b128
        float x0 = xt[(c4 * 4 + 0) * 36 + nl];          // conflict-free column
        float x1 = xt[(c4 * 4 + 1) * 36 + nl];
        float x2 = xt[(c4 * 4 + 2) * 36 + nl];
        float x3 = xt[(c4 * 4 + 3) * 36 + nl];
        qa = fmaf(wq.x, x0, qa); ka = fmaf(wk.x, x0, ka); va = fmaf(wv.x, x0, va);
        qa = fmaf(wq.y, x1, qa); ka = fmaf(wk.y, x1, ka); va = fmaf(wv.y, x1, va);
        qa = fmaf(wq.z, x2, qa); ka = fmaf(wk.z, x2, ka); va = fmaf(wv.z, x2, va);
        qa = fmaf(wq.w, x3, qa); ka = fmaf(wk.w, x3, ka); va = fmaf(wv.w, x3, va);
    }
    __bf16 vb = (__bf16)va;
    vbh[((size_t)b * CI + i) * NN + n] = vb;
    __bf16 qb = (__bf16)qa, kb2 = (__bf16)ka;
    sq[nl * 8 + i] = *(unsigned short*)&qb;
    sk[nl * 8 + i] = *(unsigned short*)&kb2;
    __syncthreads();
    if (t < 32) {
        *(uint4*)(qbh + ((size_t)b * NN + n0 + t) * 8) = *(const uint4*)(sq + t * 8);
        *(uint4*)(kbh + ((size_t)b * NN + n0 + t) * 8) = *(const uint4*)(sk + t * 8);
    }
}

// 32x32-tile MFMA attention, LDS-free (cvt_pk + permlane32_swap transpose).
// Round-6 post-mortem: att is PINNED at 41-42us across every inner-loop
// structure tried (LDS transpose 41.2, permlane variants 41.0-42.6, simple
// 41.5), and the only mover was NSPLIT=16 -> 48us, which doubled exactly one
// thing: ATOMIC traffic. Diagnosis: the epilogue's atomicAdds hit the same
// attab words from all 8 splits (2.6M atomics, 128 per cacheline) and
// serialize at L2 in an end-of-kernel burst (~45us drain by arithmetic —
// matches the invariant). Round 7 removes atomics entirely: each (b, split)
// writes a PRIVATE slice attab[b][split][9][N] with plain coalesced stores
// (each word written by exactly one lane); red_kernel reduces the slices.
// Inner loop identical to round 6 for attribution.
// S C-layout (HW-verified): col=lane&31, row=(reg&3)+8*(reg>>2)+4*(lane>>5).
// |scores| < ~2 -> exp without max-subtraction safe.
// Grid (NN/128, NSPLIT, BB) = 2048 blocks x 4 waves; wave = 32-m x 512-n tile.
__global__ __launch_bounds__(256) void att_kernel(
        const __bf16* __restrict__ qbh, const __bf16* __restrict__ kbh,
        const __bf16* __restrict__ vbh, float* __restrict__ attab) {
    const int t = threadIdx.x;
    const int w    = t >> 6;
    const int l    = t & 63;
    const int ln   = l & 31;        // S: A-row (n) / B-col (m); C col (m)
    const int hi   = l >> 5;        // k-half selector (k = hi*8 + j)
    const int b  = blockIdx.z;
    const int m0 = blockIdx.x * 128 + w * 32;
    const int nbase = blockIdx.y * (NN / NSPLIT);   // 512 per wave
    const int NCH = (NN / NSPLIT) / 32;             // 16 chunks of 32 n

    bf16x8 zero8;
#pragma unroll
    for (int z = 0; z < 8; ++z) zero8[z] = (__bf16)0.0f;
    const v16f vzero = {0.f,0.f,0.f,0.f,0.f,0.f,0.f,0.f,
                        0.f,0.f,0.f,0.f,0.f,0.f,0.f,0.f};

    // S B-frag (loop-invariant): B[k=hi*8+j][col=ln] = K[m0+ln][j], hi==0 live.
    // k=8..15 rows ZERO -> the hi=1 half of the A-frag may hold anything.
    bf16x8 kfragB = hi ? zero8
                       : *(const bf16x8*)(kbh + ((size_t)b * NN + m0 + ln) * 8);

    const __bf16* qrow = qbh + (size_t)b * NN * 8;
    // PV A-frag row = ln; rows 8..31 alias rows 0..7 (garbage rows, C 8..31
    // never read). 8 distinct addresses -> HW broadcast load.
    const __bf16* vrow = vbh + ((size_t)b * CI + (ln & 7)) * NN;

    v16f acc = vzero;
    float den = 0.f;

    for (int ch = 0; ch < NCH; ++ch) {
        const int nc = nbase + ch * 32;
        bf16x8 qf  = *(const bf16x8*)(qrow + (size_t)(nc + ln) * 8);
        bf16x8 va0 = *(const bf16x8*)(vrow + nc + hi * 8);
        bf16x8 va1 = *(const bf16x8*)(vrow + nc + 16 + hi * 8);

        v16f S = __builtin_amdgcn_mfma_f32_32x32x16_bf16(qf, kfragB, vzero,
                                                         0, 0, 0);

        float e0  = fast_exp2(S[0]),  e1  = fast_exp2(S[1]);
        float e2  = fast_exp2(S[2]),  e3  = fast_exp2(S[3]);
        float e4  = fast_exp2(S[4]),  e5  = fast_exp2(S[5]);
        float e6  = fast_exp2(S[6]),  e7  = fast_exp2(S[7]);
        float e8  = fast_exp2(S[8]),  e9  = fast_exp2(S[9]);
        float e10 = fast_exp2(S[10]), e11 = fast_exp2(S[11]);
        float e12 = fast_exp2(S[12]), e13 = fast_exp2(S[13]);
        float e14 = fast_exp2(S[14]), e15 = fast_exp2(S[15]);

        // Denominator partial for col m=ln (16 n-values this lane holds).
        den += (((e0 + e1) + (e2 + e3)) + ((e4 + e5) + (e6 + e7)))
             + (((e8 + e9) + (e10 + e11)) + ((e12 + e13) + (e14 + e15)));

        unsigned int pk0 = cvt_pk_bf16(e0,  e1);
        unsigned int pk1 = cvt_pk_bf16(e2,  e3);
        unsigned int pk2 = cvt_pk_bf16(e4,  e5);
        unsigned int pk3 = cvt_pk_bf16(e6,  e7);
        unsigned int pk4 = cvt_pk_bf16(e8,  e9);
        unsigned int pk5 = cvt_pk_bf16(e10, e11);
        unsigned int pk6 = cvt_pk_bf16(e12, e13);
        unsigned int pk7 = cvt_pk_bf16(e14, e15);

        // Lane-half exchange -> PV B-frags B[k=hi*8+j][col=ln] = E[n][m]
        u32x2 r02 = __builtin_amdgcn_permlane32_swap(pk0, pk2, false, false);
        u32x2 r13 = __builtin_amdgcn_permlane32_swap(pk1, pk3, false, false);
        u32x2 r46 = __builtin_amdgcn_permlane32_swap(pk4, pk6, false, false);
        u32x2 r57 = __builtin_amdgcn_permlane32_swap(pk5, pk7, false, false);

        union { unsigned int u[4]; bf16x8 f; } e0f, e1f;
        e0f.u[0] = r02[0]; e0f.u[1] = r13[0]; e0f.u[2] = r02[1]; e0f.u[3] = r13[1];
        e1f.u[0] = r46[0]; e1f.u[1] = r57[0]; e1f.u[2] = r46[1]; e1f.u[3] = r57[1];

        acc = __builtin_amdgcn_mfma_f32_32x32x16_bf16(va0, e0f.f, acc, 0, 0, 0);
        acc = __builtin_amdgcn_mfma_f32_32x32x16_bf16(va1, e1f.f, acc, 0, 0, 0);
    }

    // Epilogue: PLAIN STORES into this split's private slice (no atomics).
    // C row io = r + 4*hi for r=0..3 -> rows 0..7; den -> row 8.
    // Exclusive writer per word: (split=blockIdx.y, m=m0+ln, io) unique.
    float* ap = attab + (((size_t)b * NSPLIT + blockIdx.y) * 9) * NN + m0 + ln;
#pragma unroll
    for (int r = 0; r < 4; ++r)
        ap[(size_t)(r + 4 * hi) * NN] = acc[r];
    float dtot = den + __shfl_xor(den, 32, 64);
    if (hi == 0)
        ap[(size_t)8 * NN] = dtot;
}

// Split-reduction: attab [BB][NSPLIT][9][NN] -> attab2 [BB][9][NN].
// Grid: BB*9*NN/4/256 = 288 blocks x 256 threads, one v4f per thread.
// Traffic 10.6 MB, fully coalesced.
__global__ __launch_bounds__(256) void red_kernel(
        const float* __restrict__ attab, float* __restrict__ attab2) {
    const int idx = blockIdx.x * 256 + threadIdx.x;   // v4f index
    const int PERB = 9 * NN / 4;                      // 9216 v4f per batch
    const int bq = idx / PERB;
    const int r  = idx - bq * PERB;                   // (io, m4) flat
    const float* p = attab + ((size_t)bq * NSPLIT * 9) * NN + (size_t)r * 4;
    v4f s = {0.f, 0.f, 0.f, 0.f};
#pragma unroll
    for (int sp = 0; sp < NSPLIT; ++sp) {
        v4f v = *(const v4f*)(p + (size_t)sp * 9 * NN);
        s.x += v.x; s.y += v.y; s.z += v.z; s.w += v.w;
    }
    *(v4f*)(attab2 + (size_t)bq * 9 * NN + (size_t)r * 4) = s;
}

// R7-proven out (unchanged; reads reduced attab2). Grid (NN/1024, CC, BB).
__global__ __launch_bounds__(256) void out_kernel(
        const float* __restrict__ x, const float* __restrict__ Wout,
        const float* __restrict__ attab2, float* __restrict__ out) {
    const int t = threadIdx.x;
    const int c = blockIdx.y;
    const int b = blockIdx.z;
    const int m = (blockIdx.x * 256 + t) * 4;
    const float* ap = attab2 + (size_t)b * 9 * NN + m;
    v4f sum = *(const v4f*)(ap + (size_t)8 * NN);
    v4f s = {0.f, 0.f, 0.f, 0.f};
#pragma unroll
    for (int i = 0; i < CI; ++i) {
        float wgt = Wout[c * CI + i];               // uniform -> s_load
        v4f a = *(const v4f*)(ap + (size_t)i * NN);
        s.x = fmaf(wgt, a.x, s.x);
        s.y = fmaf(wgt, a.y, s.y);
        s.z = fmaf(wgt, a.z, s.z);
        s.w = fmaf(wgt, a.w, s.w);
    }
    size_t o = ((size_t)b * CC + c) * NN + m;
    v4f xv = *(const v4f*)(x + o);
    v4f r;
    r.x = xv.x + GAMMA * (s.x / sum.x);
    r.y = xv.y + GAMMA * (s.y / sum.y);
    r.z = xv.z + GAMMA * (s.z / sum.z);
    r.w = xv.w + GAMMA * (s.w / sum.w);
    *(v4f*)(out + o) = r;
}

extern "C" void kernel_launch(void* const* d_in, const int* in_sizes, int n_in,
                              void* d_out, int out_size, void* d_ws, size_t ws_size,
                              hipStream_t stream) {
    const float* x    = (const float*)d_in[0];
    const float* Wq   = (const float*)d_in[1];
    const float* Wk   = (const float*)d_in[2];
    const float* Wv   = (const float*)d_in[3];
    const float* Wout = (const float*)d_in[4];
    float* out = (float*)d_out;

    // ws: qbh [B][N][8] bf16 | kbh [B][N][8] bf16 | vbh [B][8][N] bf16 |
    //     attab [B][NSPLIT][9][N] fp32 | attab2 [B][9][N] fp32
    __bf16* qbh = (__bf16*)d_ws;
    __bf16* kbh = qbh + (size_t)BB * NN * 8;
    __bf16* vbh = kbh + (size_t)BB * NN * 8;
    float* attab  = (float*)(vbh + (size_t)BB * NN * 8);
    float* attab2 = attab + (size_t)BB * NSPLIT * 9 * NN;

    qkv_kernel<<<dim3(NN / 32, BB), 256, 0, stream>>>(x, Wq, Wk, Wv, qbh, kbh, vbh);
    att_kernel<<<dim3(NN / 128, NSPLIT, BB), 256, 0, stream>>>(qbh, kbh, vbh, attab);
    red_kernel<<<dim3(BB * 9 * NN / 4 / 256), 256, 0, stream>>>(attab, attab2);
    out_kernel<<<dim3(NN / 1024, CC, BB), 256, 0, stream>>>(x, Wout, attab2, out);
}

// Round 8
// 107.774 us; speedup vs baseline: 1.0878x; 1.0878x over previous
//
#include <hip/hip_runtime.h>
#include <math.h>

#define BB 8
#define CC 64
#define NN 4096
#define CI 8
#define GAMMA 0.1f
// exp(s/sqrt(8)) = exp2(s * log2(e)/sqrt(8)); folded into k in qkv.
#define SCALE (1.44269504088896f * 0.35355339059327f)
#define NSPLIT 8

typedef float v4f  __attribute__((ext_vector_type(4)));
typedef float v16f __attribute__((ext_vector_type(16)));
typedef __bf16 bf16x8 __attribute__((ext_vector_type(8)));
typedef unsigned int u32x2 __attribute__((ext_vector_type(2)));

__device__ __forceinline__ float fast_exp2(float x) {
    return __builtin_amdgcn_exp2f(x);
}

// Pack two f32 into one u32 of 2 bf16 (T12 recipe; no builtin on gfx950).
__device__ __forceinline__ unsigned int cvt_pk_bf16(float lo, float hi) {
    unsigned int r;
    asm("v_cvt_pk_bf16_f32 %0, %1, %2" : "=v"(r) : "v"(lo), "v"(hi));
    return r;
}

// qkv (round-6 form: LDS-staged x + attab zero-init restored, since the
// epilogue reverts to atomics). Grid (NN/32, BB); block 256.
// qbh[b][n][8], kbh[b][m][8] (k*SCALE), vbh[b][i][N] bf16; zeros attab[b][9][N].
__global__ __launch_bounds__(256) void qkv_kernel(
        const float* __restrict__ x,
        const float* __restrict__ Wq, const float* __restrict__ Wk,
        const float* __restrict__ Wv,
        __bf16* __restrict__ qbh, __bf16* __restrict__ kbh,
        __bf16* __restrict__ vbh, float* __restrict__ attab) {
    __shared__ float sw[3 * CI * CC];     // 6 KB: Wq | Wk*SCALE | Wv
    __shared__ float xt[CC * 36];         // 9216 B: x tile [c][n_local], pitch 36
    __shared__ unsigned short sq[32 * 8]; // bf16 tile [n_local][i]
    __shared__ unsigned short sk[32 * 8];
    const int t = threadIdx.x;
    const int b  = blockIdx.y;
    const int n0 = blockIdx.x * 32;

    for (int idx = t; idx < CI * CC; idx += 256) {
        sw[idx]                = Wq[idx];
        sw[CI * CC + idx]      = Wk[idx] * SCALE;
        sw[2 * CI * CC + idx]  = Wv[idx];
    }
    // Stage x tile: 64 c x 32 n = 512 float4; 2 per thread.
    {
        const float* xb = x + ((size_t)b * CC) * NN + n0;
#pragma unroll
        for (int j = 0; j < 2; ++j) {
            int u = t + j * 256;
            int c = u >> 3, n4 = u & 7;
            v4f xv = *(const v4f*)(xb + (size_t)c * NN + n4 * 4);
            *(v4f*)(xt + c * 36 + n4 * 4) = xv;
        }
    }
    int lin = (blockIdx.y * (NN / 32) + blockIdx.x) * 256 + t;
    for (int idx = lin; idx < BB * 9 * NN; idx += BB * NN * CI) attab[idx] = 0.f;
    __syncthreads();

    const int i  = t >> 5;
    const int nl = t & 31;
    const int n = n0 + nl;
    const v4f* wq4 = (const v4f*)(sw + i * CC);
    const v4f* wk4 = (const v4f*)(sw + CI * CC + i * CC);
    const v4f* wv4 = (const v4f*)(sw + 2 * CI * CC + i * CC);
    float qa = 0.f, ka = 0.f, va = 0.f;
#pragma unroll 4
    for (int c4 = 0; c4 < CC / 4; ++c4) {
        v4f wq = wq4[c4], wk = wk4[c4], wv = wv4[c4];   // LDS broadcast b128
        float x0 = xt[(c4 * 4 + 0) * 36 + nl];          // conflict-free column
        float x1 = xt[(c4 * 4 + 1) * 36 + nl];
        float x2 = xt[(c4 * 4 + 2) * 36 + nl];
        float x3 = xt[(c4 * 4 + 3) * 36 + nl];
        qa = fmaf(wq.x, x0, qa); ka = fmaf(wk.x, x0, ka); va = fmaf(wv.x, x0, va);
        qa = fmaf(wq.y, x1, qa); ka = fmaf(wk.y, x1, ka); va = fmaf(wv.y, x1, va);
        qa = fmaf(wq.z, x2, qa); ka = fmaf(wk.z, x2, ka); va = fmaf(wv.z, x2, va);
        qa = fmaf(wq.w, x3, qa); ka = fmaf(wk.w, x3, ka); va = fmaf(wv.w, x3, va);
    }
    __bf16 vb = (__bf16)va;
    vbh[((size_t)b * CI + i) * NN + n] = vb;
    __bf16 qb = (__bf16)qa, kb2 = (__bf16)ka;
    sq[nl * 8 + i] = *(unsigned short*)&qb;
    sk[nl * 8 + i] = *(unsigned short*)&kb2;
    __syncthreads();
    if (t < 32) {
        *(uint4*)(qbh + ((size_t)b * NN + n0 + t) * 8) = *(const uint4*)(sq + t * 8);
        *(uint4*)(kbh + ((size_t)b * NN + n0 + t) * 8) = *(const uint4*)(sk + t * 8);
    }
}

// 32x32-tile MFMA attention — DUAL M-TILE per wave.
// Round-7 post-mortem: epilogue (atomics vs stores) is irrelevant; kernel
// time ~= (blocks/CU) x (per-wave serial chunk chain ~800cy): vmcnt ~200 +
// S-MFMA + 16-exp burst + pack/swap + 2 dependent PV-MFMA. Both pipes idle
// (VALU 37%, MFMA 10%) because ~3 resident waves/SIMD all sit in the SAME
// chain shape. Fix: 2x INDEPENDENT work per wave. Each wave now owns two
// adjacent 32-m tiles sharing the chunk's q/v loads:
//   S0,S1 issued back-to-back -> tile0's exp/pack/swap/PV (trans+VALU) runs
//   while S1's MFMA latency drains; tile0's PV overlaps tile1's exp burst.
// Loads per MFMA halve. Epilogue: r6 atomic form (measured best).
// S C-layout (HW-verified): col=lane&31, row=(reg&3)+8*(reg>>2)+4*(lane>>5).
// |scores| < ~2 -> exp without max-subtraction safe.
// Grid (NN/256, NSPLIT, BB) = 1024 blocks x 4 waves; wave = 64-m x 512-n.
__global__ __launch_bounds__(256) void att_kernel(
        const __bf16* __restrict__ qbh, const __bf16* __restrict__ kbh,
        const __bf16* __restrict__ vbh, float* __restrict__ attab) {
    const int t = threadIdx.x;
    const int w    = t >> 6;
    const int l    = t & 63;
    const int ln   = l & 31;        // S: A-row (n) / B-col (m); C col (m)
    const int hi   = l >> 5;        // k-half selector (k = hi*8 + j)
    const int b  = blockIdx.z;
    const int m0 = blockIdx.x * 256 + w * 64;       // two tiles: m0, m0+32
    const int nbase = blockIdx.y * (NN / NSPLIT);   // 512 per wave
    const int NCH = (NN / NSPLIT) / 32;             // 16 chunks of 32 n

    bf16x8 zero8;
#pragma unroll
    for (int z = 0; z < 8; ++z) zero8[z] = (__bf16)0.0f;
    const v16f vzero = {0.f,0.f,0.f,0.f,0.f,0.f,0.f,0.f,
                        0.f,0.f,0.f,0.f,0.f,0.f,0.f,0.f};

    // S B-frags (loop-invariant): B[k=hi*8+j][col=ln] = K[m][j], hi==0 live.
    // k=8..15 rows ZERO -> the hi=1 half of the A-frag may hold anything.
    bf16x8 kB0 = hi ? zero8
                    : *(const bf16x8*)(kbh + ((size_t)b * NN + m0 + ln) * 8);
    bf16x8 kB1 = hi ? zero8
                    : *(const bf16x8*)(kbh + ((size_t)b * NN + m0 + 32 + ln) * 8);

    const __bf16* qrow = qbh + (size_t)b * NN * 8;
    // PV A-frag row = ln; rows 8..31 alias rows 0..7 (garbage rows, C 8..31
    // never read). 8 distinct addresses -> HW broadcast load.
    const __bf16* vrow = vbh + ((size_t)b * CI + (ln & 7)) * NN;

    v16f acc0 = vzero, acc1 = vzero;
    float den0 = 0.f, den1 = 0.f;

    for (int ch = 0; ch < NCH; ++ch) {
        const int nc = nbase + ch * 32;
        bf16x8 qf  = *(const bf16x8*)(qrow + (size_t)(nc + ln) * 8);
        bf16x8 va0 = *(const bf16x8*)(vrow + nc + hi * 8);
        bf16x8 va1 = *(const bf16x8*)(vrow + nc + 16 + hi * 8);

        // Both S MFMAs issued together: S1's latency hides under tile0's
        // exp/pack/swap below (pipe diversity: MFMA vs trans/VALU).
        v16f S0 = __builtin_amdgcn_mfma_f32_32x32x16_bf16(qf, kB0, vzero, 0, 0, 0);
        v16f S1 = __builtin_amdgcn_mfma_f32_32x32x16_bf16(qf, kB1, vzero, 0, 0, 0);

        // ---- tile 0 ----
        {
            float e0  = fast_exp2(S0[0]),  e1  = fast_exp2(S0[1]);
            float e2  = fast_exp2(S0[2]),  e3  = fast_exp2(S0[3]);
            float e4  = fast_exp2(S0[4]),  e5  = fast_exp2(S0[5]);
            float e6  = fast_exp2(S0[6]),  e7  = fast_exp2(S0[7]);
            float e8  = fast_exp2(S0[8]),  e9  = fast_exp2(S0[9]);
            float e10 = fast_exp2(S0[10]), e11 = fast_exp2(S0[11]);
            float e12 = fast_exp2(S0[12]), e13 = fast_exp2(S0[13]);
            float e14 = fast_exp2(S0[14]), e15 = fast_exp2(S0[15]);
            den0 += (((e0 + e1) + (e2 + e3)) + ((e4 + e5) + (e6 + e7)))
                  + (((e8 + e9) + (e10 + e11)) + ((e12 + e13) + (e14 + e15)));
            unsigned int pk0 = cvt_pk_bf16(e0,  e1);
            unsigned int pk1 = cvt_pk_bf16(e2,  e3);
            unsigned int pk2 = cvt_pk_bf16(e4,  e5);
            unsigned int pk3 = cvt_pk_bf16(e6,  e7);
            unsigned int pk4 = cvt_pk_bf16(e8,  e9);
            unsigned int pk5 = cvt_pk_bf16(e10, e11);
            unsigned int pk6 = cvt_pk_bf16(e12, e13);
            unsigned int pk7 = cvt_pk_bf16(e14, e15);
            u32x2 r02 = __builtin_amdgcn_permlane32_swap(pk0, pk2, false, false);
            u32x2 r13 = __builtin_amdgcn_permlane32_swap(pk1, pk3, false, false);
            u32x2 r46 = __builtin_amdgcn_permlane32_swap(pk4, pk6, false, false);
            u32x2 r57 = __builtin_amdgcn_permlane32_swap(pk5, pk7, false, false);
            union { unsigned int u[4]; bf16x8 f; } e0f, e1f;
            e0f.u[0] = r02[0]; e0f.u[1] = r13[0]; e0f.u[2] = r02[1]; e0f.u[3] = r13[1];
            e1f.u[0] = r46[0]; e1f.u[1] = r57[0]; e1f.u[2] = r46[1]; e1f.u[3] = r57[1];
            acc0 = __builtin_amdgcn_mfma_f32_32x32x16_bf16(va0, e0f.f, acc0, 0, 0, 0);
            acc0 = __builtin_amdgcn_mfma_f32_32x32x16_bf16(va1, e1f.f, acc0, 0, 0, 0);
        }
        // ---- tile 1 (S1's MFMA long since drained) ----
        {
            float e0  = fast_exp2(S1[0]),  e1  = fast_exp2(S1[1]);
            float e2  = fast_exp2(S1[2]),  e3  = fast_exp2(S1[3]);
            float e4  = fast_exp2(S1[4]),  e5  = fast_exp2(S1[5]);
            float e6  = fast_exp2(S1[6]),  e7  = fast_exp2(S1[7]);
            float e8  = fast_exp2(S1[8]),  e9  = fast_exp2(S1[9]);
            float e10 = fast_exp2(S1[10]), e11 = fast_exp2(S1[11]);
            float e12 = fast_exp2(S1[12]), e13 = fast_exp2(S1[13]);
            float e14 = fast_exp2(S1[14]), e15 = fast_exp2(S1[15]);
            den1 += (((e0 + e1) + (e2 + e3)) + ((e4 + e5) + (e6 + e7)))
                  + (((e8 + e9) + (e10 + e11)) + ((e12 + e13) + (e14 + e15)));
            unsigned int pk0 = cvt_pk_bf16(e0,  e1);
            unsigned int pk1 = cvt_pk_bf16(e2,  e3);
            unsigned int pk2 = cvt_pk_bf16(e4,  e5);
            unsigned int pk3 = cvt_pk_bf16(e6,  e7);
            unsigned int pk4 = cvt_pk_bf16(e8,  e9);
            unsigned int pk5 = cvt_pk_bf16(e10, e11);
            unsigned int pk6 = cvt_pk_bf16(e12, e13);
            unsigned int pk7 = cvt_pk_bf16(e14, e15);
            u32x2 r02 = __builtin_amdgcn_permlane32_swap(pk0, pk2, false, false);
            u32x2 r13 = __builtin_amdgcn_permlane32_swap(pk1, pk3, false, false);
            u32x2 r46 = __builtin_amdgcn_permlane32_swap(pk4, pk6, false, false);
            u32x2 r57 = __builtin_amdgcn_permlane32_swap(pk5, pk7, false, false);
            union { unsigned int u[4]; bf16x8 f; } e0f, e1f;
            e0f.u[0] = r02[0]; e0f.u[1] = r13[0]; e0f.u[2] = r02[1]; e0f.u[3] = r13[1];
            e1f.u[0] = r46[0]; e1f.u[1] = r57[0]; e1f.u[2] = r46[1]; e1f.u[3] = r57[1];
            acc1 = __builtin_amdgcn_mfma_f32_32x32x16_bf16(va0, e0f.f, acc1, 0, 0, 0);
            acc1 = __builtin_amdgcn_mfma_f32_32x32x16_bf16(va1, e1f.f, acc1, 0, 0, 0);
        }
    }

    // Epilogue (r6 atomic form, measured best): C row io = r + 4*hi,
    // r=0..3 -> rows 0..7; den -> row 8. Two m-tiles.
    float* ap0 = attab + (size_t)b * 9 * NN + m0 + ln;
    float* ap1 = ap0 + 32;
#pragma unroll
    for (int r = 0; r < 4; ++r) {
        atomicAdd(ap0 + (size_t)(r + 4 * hi) * NN, acc0[r]);
        atomicAdd(ap1 + (size_t)(r + 4 * hi) * NN, acc1[r]);
    }
    float d0 = den0 + __shfl_xor(den0, 32, 64);
    float d1 = den1 + __shfl_xor(den1, 32, 64);
    if (hi == 0) {
        atomicAdd(ap0 + (size_t)8 * NN, d0);
        atomicAdd(ap1 + (size_t)8 * NN, d1);
    }
}

// R7-proven out. Grid (NN/1024, CC, BB); block 256; float4 per thread.
__global__ __launch_bounds__(256) void out_kernel(
        const float* __restrict__ x, const float* __restrict__ Wout,
        const float* __restrict__ attab, float* __restrict__ out) {
    const int t = threadIdx.x;
    const int c = blockIdx.y;
    const int b = blockIdx.z;
    const int m = (blockIdx.x * 256 + t) * 4;
    const float* ap = attab + (size_t)b * 9 * NN + m;
    v4f sum = *(const v4f*)(ap + (size_t)8 * NN);
    v4f s = {0.f, 0.f, 0.f, 0.f};
#pragma unroll
    for (int i = 0; i < CI; ++i) {
        float wgt = Wout[c * CI + i];               // uniform -> s_load
        v4f a = *(const v4f*)(ap + (size_t)i * NN);
        s.x = fmaf(wgt, a.x, s.x);
        s.y = fmaf(wgt, a.y, s.y);
        s.z = fmaf(wgt, a.z, s.z);
        s.w = fmaf(wgt, a.w, s.w);
    }
    size_t o = ((size_t)b * CC + c) * NN + m;
    v4f xv = *(const v4f*)(x + o);
    v4f r;
    r.x = xv.x + GAMMA * (s.x / sum.x);
    r.y = xv.y + GAMMA * (s.y / sum.y);
    r.z = xv.z + GAMMA * (s.z / sum.z);
    r.w = xv.w + GAMMA * (s.w / sum.w);
    *(v4f*)(out + o) = r;
}

extern "C" void kernel_launch(void* const* d_in, const int* in_sizes, int n_in,
                              void* d_out, int out_size, void* d_ws, size_t ws_size,
                              hipStream_t stream) {
    const float* x    = (const float*)d_in[0];
    const float* Wq   = (const float*)d_in[1];
    const float* Wk   = (const float*)d_in[2];
    const float* Wv   = (const float*)d_in[3];
    const float* Wout = (const float*)d_in[4];
    float* out = (float*)d_out;

    // ws: qbh [B][N][8] bf16 | kbh [B][N][8] bf16 | vbh [B][8][N] bf16 |
    //     attab [B][9][N] fp32
    __bf16* qbh = (__bf16*)d_ws;
    __bf16* kbh = qbh + (size_t)BB * NN * 8;
    __bf16* vbh = kbh + (size_t)BB * NN * 8;
    float* attab = (float*)(vbh + (size_t)BB * NN * 8);

    qkv_kernel<<<dim3(NN / 32, BB), 256, 0, stream>>>(x, Wq, Wk, Wv, qbh, kbh, vbh, attab);
    att_kernel<<<dim3(NN / 256, NSPLIT, BB), 256, 0, stream>>>(qbh, kbh, vbh, attab);
    out_kernel<<<dim3(NN / 1024, CC, BB), 256, 0, stream>>>(x, Wout, attab, out);
}